// Round 10
// baseline (331.247 us; speedup 1.0000x reference)
//
#include <hip/hip_runtime.h>
#include <hip/hip_bf16.h>

// SynthesisBlock: modulated 3x3 conv (StyleGAN2-style) on MI355X.
// R10: 8-wave (512-thread) block, 64co x 16rows x 64px tile, 1 block/CU.
//   - 2 waves/SIMD (launch_bounds(512,2)) -> partner wave feeds MFMA pipe
//     while the other drains LDS reads (R7 evidence: 2/SIMD=66%, 1/SIMD=53%).
//   - 16-row tile: halo stage traffic 2.75->2.44 KB/row, W staged 1x per 16
//     rows, 2 generations instead of 4.
//   - phases/operand layout identical to R7 (verified absmax 0.031).
//   - xsprep rewritten LDS-free (direct strided-coalesced reads).

typedef float f32x4 __attribute__((ext_vector_type(4)));
typedef float f32x16 __attribute__((ext_vector_type(16)));
typedef short bf16x8 __attribute__((ext_vector_type(8)));
typedef int i32x4 __attribute__((ext_vector_type(4)));

#define BB 16
#define CIN 512
#define COUT 512
#define HH 64
#define WW 64
#define LL 512

// xs3: [b 16][c16 32][rowidx 66 (= y+1)][h 2][px' 68][ci8 8] bf16
#define X3ROWB 2176
#define X3C16B (66 * X3ROWB)            // 143616
#define X3BB (32 * X3C16B)              // 4595712
#define XS3_SZ (16 * X3BB)              // 73531392

// wt3: [cib 32][tap 9][h 2][co 512][ci8 8] bf16
#define WT3_STEPB 147456
#define WT3_SZ (32 * WT3_STEPB)

#define XS3_OFF 0
#define WT3_OFF XS3_SZ
#define STYLE_OFF (WT3_OFF + WT3_SZ)
#define STYLE_SZ (BB * CIN * 4)
#define WSQ_OFF (STYLE_OFF + STYLE_SZ)
#define WSQ_SZ (COUT * CIN * 4)
#define DEM_OFF (WSQ_OFF + WSQ_SZ)
#define DEM_SZ (BB * COUT * 4)
#define WS_NEEDED (DEM_OFF + DEM_SZ)

// conv LDS: X slab = 18 rows x 2176 = 39168 B, staged as 39 KB-chunks
// (chunk 38 over-reads 768 B of slack -- never read back). W = 18 KB.
#define XCH 39
#define XBUFB (XCH * 1024)              // 39936
#define WCH 18
#define WBUFB (WCH * 1024)              // 18432
#define NCH (XCH + WCH)                 // 57

__device__ __forceinline__ void gld_lds16(const void* g, void* l) {
  __builtin_amdgcn_global_load_lds(
      (const __attribute__((address_space(1))) unsigned int*)g,
      (__attribute__((address_space(3))) unsigned int*)l, 16, 0, 0);
}

// ---------------- K1: style ----------------
__global__ void style_kernel(const float* __restrict__ latent,
                             const float* __restrict__ affine_w,
                             const float* __restrict__ affine_b,
                             float* __restrict__ style) {
  const int idx = blockIdx.x * 256 + threadIdx.x;   // 8192
  const int b = idx >> 9, ci = idx & 511;
  const float* lp = latent + b * LL;
  const float* wp = affine_w + ci * LL;
  float acc = 0.f;
  for (int l = 0; l < LL; ++l) acc += lp[l] * wp[l];
  style[idx] = acc * 0.044194173824159216f + affine_b[ci];  // sqrt(1/512)
}

// ---------------- K2: weight sumsq + wt3 layout ----------------
__global__ void wprep_kernel(const float* __restrict__ conv_w,
                             float* __restrict__ wsq,
                             __hip_bfloat16* __restrict__ wt3) {
  const int idx = blockIdx.x * 256 + threadIdx.x;   // 262144 = co*512+ci
  const int co = idx >> 9, ci = idx & 511;
  const float* wp = conv_w + idx * 9;
  const int cib = ci >> 4, h = (ci >> 3) & 1, ci8 = ci & 7;
  __hip_bfloat16* base = wt3 + (size_t)cib * 73728 + h * 4096 + co * 8 + ci8;
  float ss = 0.f;
#pragma unroll
  for (int t = 0; t < 9; ++t) {
    float v = wp[t];
    ss += v * v;
    base[t * 8192] = __float2bfloat16(v);
  }
  wsq[idx] = ss;
}

// ---------------- K3: demodulation scale ----------------
__global__ void dem_kernel(const float* __restrict__ wsq,
                           const float* __restrict__ style,
                           float* __restrict__ dem) {
  const int idx = blockIdx.x * 256 + threadIdx.x;   // 8192 = b*512+co
  const int b = idx >> 9, co = idx & 511;
  const float* sp = style + b * CIN;
  const float* wp = wsq + co * CIN;
  float acc = 0.f;
  for (int ci = 0; ci < CIN; ++ci) {
    float s = sp[ci];
    acc += wp[ci] * s * s;
  }
  dem[idx] = 1.0f / sqrtf(acc + 1e-8f);
}

// ---------------- K4: modulate + layout (LDS-free) ----------------
__global__ void xsprep_kernel(const float* __restrict__ content,
                              const float* __restrict__ style,
                              char* __restrict__ xs3) {
  const int b = blockIdx.x >> 6;
  const int y = blockIdx.x & 63;
  const int tid = threadIdx.x;
  char* bbase = xs3 + (size_t)b * X3BB;

  // zero px' pads {0,65,66,67} of own row: 32 c16 x 2 h x 4 px = 256 units
  {
    const int c16 = tid >> 3, rest = tid & 7;
    const int h = rest >> 2, pp = rest & 3;
    const int pxp = (pp == 0) ? 0 : 64 + pp;
    *(i32x4*)(bbase + (size_t)c16 * X3C16B + (y + 1) * X3ROWB + h * 1088 +
              pxp * 16) = (i32x4){0, 0, 0, 0};
  }
  // edge blocks zero the halo rows (rowidx 0 / 65)
  if (y == 0 || y == 63) {
    const int rowidx = (y == 0) ? 0 : 65;
#pragma unroll
    for (int k = 0; k < 17; ++k) {
      const int u = tid + k * 256;
      if (u < 4352) {
        const int c16 = u / 136, w = u - c16 * 136;
        *(i32x4*)(bbase + (size_t)c16 * X3C16B + rowidx * X3ROWB + w * 16) =
            (i32x4){0, 0, 0, 0};
      }
    }
  }

  // main: oct = ci>>3 (64 of them) over 4 waves; lane = px.
  const int px = tid & 63;
  const int wq = tid >> 6;
  for (int oct = wq; oct < 64; oct += 4) {
    const int c16 = oct >> 1, h = oct & 1;
    const float* cp = content + ((size_t)(b * CIN + oct * 8) * HH + y) * WW + px;
    const float* sp = style + b * CIN + oct * 8;
    bf16x8 v;
#pragma unroll
    for (int j = 0; j < 8; ++j)
      v[j] = __bfloat16_as_short(__float2bfloat16(cp[j * 4096] * sp[j]));
    *(bf16x8*)(bbase + (size_t)c16 * X3C16B + (y + 1) * X3ROWB + h * 1088 +
               (px + 1) * 16) = v;
  }
}

// ---------------- K5: main MFMA conv ----------------
// grid 512 (16b x 4yo x 8cot, XCD-swizzled), 512 threads (8 waves).
// Block: 64co x 16rows x 64px; wave wv owns rows y0+2wv..+1 (mf2,r2,q2).
__global__ __launch_bounds__(512, 2) void conv_kernel(
    const char* __restrict__ xs3,
    const char* __restrict__ wt3,
    const float* __restrict__ dem,
    const float* __restrict__ noise,
    const float* __restrict__ biasp,
    const float* __restrict__ nwp,
    float* __restrict__ out) {
  __shared__ __attribute__((aligned(16))) char xlds[2][XBUFB];
  __shared__ __attribute__((aligned(16))) char wlds[2][WBUFB];

  const int tid = threadIdx.x;
  const int lane = tid & 63;
  const int wv = tid >> 6;                  // 0..7
  const int l31 = lane & 31;
  const int hsel = lane >> 5;

  const int d = blockIdx.x;                 // 0..511
  const int L = (d & 7) * 64 + (d >> 3);    // bijective XCD swizzle (512%8==0)
  const int cot = L & 7;
  const int yo = (L >> 3) & 3;
  const int b = L >> 5;
  const int co0 = cot << 6;
  const int y0 = yo << 4;

  // stage chunk sources (step 0): chunk c = wv + 8k; X slab is contiguous
  // [rowidx y0 .. y0+17] of (b, c16=t); W chunk j=(2tap+h).
  const char* gsrc[8];
#pragma unroll
  for (int k = 0; k < 8; ++k) {
    const int c = wv + 8 * k;
    if (c < XCH)
      gsrc[k] = xs3 + (size_t)b * X3BB + (size_t)y0 * X3ROWB + c * 1024 +
                lane * 16;
    else if (c < NCH)
      gsrc[k] = wt3 + (c - XCH) * 8192 + (co0 + lane) * 16;
    else
      gsrc[k] = xs3;
  }

  const int abase0 = hsel * 1024 + l31 * 16;  // + (dy*3+dx)*2048 + mf*512
  const int bbase0 = hsel * 1088 + l31 * 16;  // + (2wv+ir)*2176 + (q*32+dx)*16
  const int xwrow = 2 * wv * X3ROWB;

  f32x16 acc[2][2][2];
#pragma unroll
  for (int mf = 0; mf < 2; ++mf)
#pragma unroll
    for (int r = 0; r < 2; ++r)
#pragma unroll
      for (int q = 0; q < 2; ++q)
#pragma unroll
        for (int e = 0; e < 16; ++e) acc[mf][r][q][e] = 0.f;

#define STG_ALL(TT, BI)                                                    \
  {                                                                        \
    _Pragma("unroll") for (int k = 0; k < 8; ++k) {                        \
      const int c = wv + 8 * k;                                            \
      if (c < XCH)                                                         \
        gld_lds16(gsrc[k] + (size_t)(TT) * X3C16B, xlds[BI] + c * 1024);   \
      else if (c < NCH)                                                    \
        gld_lds16(gsrc[k] + (size_t)(TT) * WT3_STEPB,                      \
                  wlds[BI] + (c - XCH) * 1024);                            \
    }                                                                      \
  }

#define PHASE(DX, DOSTG, DOVM)                                             \
  {                                                                        \
    bf16x8 aP[3][2], bP[4][2];                                             \
    _Pragma("unroll") for (int dy = 0; dy < 3; ++dy)                       \
        _Pragma("unroll") for (int mf = 0; mf < 2; ++mf)                   \
            aP[dy][mf] = *(const bf16x8*)(wb + (dy * 3 + (DX)) * 2048 +    \
                                          abase0 + mf * 512);              \
    _Pragma("unroll") for (int ir = 0; ir < 4; ++ir)                       \
        _Pragma("unroll") for (int q = 0; q < 2; ++q)                      \
            bP[ir][q] = *(const bf16x8*)(xb + xwrow + ir * X3ROWB +        \
                                         bbase0 + (q * 32 + (DX)) * 16);   \
    if ((DOSTG) && t < 31) STG_ALL(t + 1, bi ^ 1)                          \
    __builtin_amdgcn_s_barrier();                                          \
    asm volatile("s_waitcnt lgkmcnt(0)" ::: "memory");                     \
    __builtin_amdgcn_sched_barrier(0);                                     \
    __builtin_amdgcn_s_setprio(1);                                         \
    _Pragma("unroll") for (int ir = 0; ir < 4; ++ir)                       \
        _Pragma("unroll") for (int dy = 0; dy < 3; ++dy) {                 \
      const int rr = ir - dy;                                              \
      if (rr == 0 || rr == 1) {                                            \
        _Pragma("unroll") for (int q = 0; q < 2; ++q)                      \
            _Pragma("unroll") for (int mf = 0; mf < 2; ++mf)               \
                acc[mf][rr][q] = __builtin_amdgcn_mfma_f32_32x32x16_bf16(  \
                    aP[dy][mf], bP[ir][q], acc[mf][rr][q], 0, 0, 0);       \
      }                                                                    \
    }                                                                      \
    __builtin_amdgcn_s_setprio(0);                                         \
    if (DOVM) asm volatile("s_waitcnt vmcnt(0)" ::: "memory");             \
    __builtin_amdgcn_s_barrier();                                          \
  }

  // prologue: stage step 0 -> buf0
  STG_ALL(0, 0)
  asm volatile("s_waitcnt vmcnt(0)" ::: "memory");
  __builtin_amdgcn_s_barrier();

  for (int t = 0; t < 32; ++t) {
    const int bi = t & 1;
    const char* xb = xlds[bi];
    const char* wb = wlds[bi];
    PHASE(0, 1, 0)
    PHASE(1, 0, 0)
    PHASE(2, 0, 1)
  }
#undef PHASE
#undef STG_ALL

  // ---- epilogue: demod scale, noise, bias, lrelu*sqrt(2) ----
  const float nwv = nwp[0];
  float nz[2][2];
#pragma unroll
  for (int r = 0; r < 2; ++r) {
    const int y = y0 + 2 * wv + r;
#pragma unroll
    for (int q = 0; q < 2; ++q)
      nz[r][q] = nwv * noise[(b << 12) + (y << 6) + q * 32 + l31];
  }
#pragma unroll
  for (int mf = 0; mf < 2; ++mf)
#pragma unroll
    for (int reg = 0; reg < 16; ++reg) {
      const int coo = (reg & 3) + 8 * (reg >> 2) + 4 * hsel;
      const int co = co0 + mf * 32 + coo;
      const float dv = dem[(b << 9) + co];
      const float bv = biasp[co];
#pragma unroll
      for (int r = 0; r < 2; ++r) {
        const int y = y0 + 2 * wv + r;
#pragma unroll
        for (int q = 0; q < 2; ++q) {
          float v = acc[mf][r][q][reg] * dv + nz[r][q] + bv;
          v = (v > 0.f ? v : 0.2f * v) * 1.41421356237309515f;
          out[(((size_t)(b << 9) + co) << 12) + (y << 6) + q * 32 + l31] = v;
        }
      }
    }
}

extern "C" void kernel_launch(void* const* d_in, const int* in_sizes, int n_in,
                              void* d_out, int out_size, void* d_ws, size_t ws_size,
                              hipStream_t stream) {
  const float* content  = (const float*)d_in[0];
  const float* latent   = (const float*)d_in[1];
  const float* noise    = (const float*)d_in[2];
  const float* affine_w = (const float*)d_in[3];
  const float* affine_b = (const float*)d_in[4];
  const float* conv_w   = (const float*)d_in[5];
  const float* bias     = (const float*)d_in[6];
  const float* nw       = (const float*)d_in[7];
  float* out = (float*)d_out;
  char* ws = (char*)d_ws;

  if (ws_size < (size_t)WS_NEEDED) return;

  char* xs3 = ws + XS3_OFF;
  __hip_bfloat16* wt3 = (__hip_bfloat16*)(ws + WT3_OFF);
  float* style = (float*)(ws + STYLE_OFF);
  float* wsq   = (float*)(ws + WSQ_OFF);
  float* dem   = (float*)(ws + DEM_OFF);

  style_kernel<<<dim3(32), dim3(256), 0, stream>>>(latent, affine_w, affine_b, style);
  wprep_kernel<<<dim3(1024), dim3(256), 0, stream>>>(conv_w, wsq, wt3);
  dem_kernel<<<dim3(32), dim3(256), 0, stream>>>(wsq, style, dem);
  xsprep_kernel<<<dim3(1024), dim3(256), 0, stream>>>(content, style, xs3);
  conv_kernel<<<dim3(512), dim3(512), 0, stream>>>(
      xs3, (const char*)(ws + WT3_OFF), dem, noise, bias, nw, out);
}